// Round 4
// baseline (612.579 us; speedup 1.0000x reference)
//
#include <hip/hip_runtime.h>
#include <math.h>

// Problem constants
#define B   32
#define TU  128
#define TM  128
#define TZ  32
#define TENC 288
#define V   10000
#define H   512
#define E   128
#define S   640          // E + H
#define G3  1536         // 3*H
#define NLOG (V + TENC)  // 10288

// Workspace float region (float offsets)
#define WS_Q      0                       // B*H
#define WS_SCORE  (WS_Q + B*H)            // B*TENC
#define WS_CTX    (WS_SCORE + B*TENC)     // B*H
#define WS_GI     (WS_CTX + B*H)          // B*G3
#define WS_GH     (WS_GI + B*G3)          // B*G3
#define WS_ST     (WS_GH + B*G3)          // B*S
#define WS_LOGIT  (WS_ST + B*S)           // B*NLOG
#define WS_PCOPY  (WS_LOGIT + B*NLOG)     // B*TENC
#define WS_F_TOTAL (WS_PCOPY + B*TENC)

// bf16 (ushort) region: only weights with >1 reuse get pre-converted.
// W_gen / W_attn[:, :H] / W_ih / W_hh are read once -> inline cvt in consumers.
#define BF_WA2  0                         // W_attn[:, H:]  as [g][k], 512*512
#define BF_WCP  (BF_WA2 + 512*512)        // W_cpu|W_cpm|W_cppz, each 640*512

typedef __attribute__((ext_vector_type(8))) short bf16x8_t;
typedef __attribute__((ext_vector_type(4))) float f32x4_t;
typedef __attribute__((ext_vector_type(16))) float f32x16_t;

__device__ __forceinline__ float fast_tanh(float x) {
    return 1.f - 2.f / (__expf(2.f * x) + 1.f);
}

__device__ __forceinline__ unsigned short f2bf(float x) {
    unsigned int u = __float_as_uint(x);
    u += 0x7fffu + ((u >> 16) & 1u);   // RNE
    return (unsigned short)(u >> 16);
}

// 8 consecutive fp32 -> bf16x8 fragment
__device__ __forceinline__ bf16x8_t cvt8(const float* p) {
    float4 a = *(const float4*)(p);
    float4 b = *(const float4*)(p + 4);
    bf16x8_t r;
    r[0] = (short)f2bf(a.x); r[1] = (short)f2bf(a.y);
    r[2] = (short)f2bf(a.z); r[3] = (short)f2bf(a.w);
    r[4] = (short)f2bf(b.x); r[5] = (short)f2bf(b.y);
    r[6] = (short)f2bf(b.z); r[7] = (short)f2bf(b.w);
    return r;
}

__device__ __forceinline__ const float* enc_row(const float* u, const float* m,
                                                const float* pz, int b, int t) {
    if (t < TU) return u + ((size_t)b * TU + t) * H;
    if (t < TU + TM) return m + ((size_t)b * TM + (t - TU)) * H;
    return pz + ((size_t)b * TZ + (t - TU - TM)) * H;
}

// ---------------- K0: cvt only the reused weights (WA2 + WCP) --------------
#define CVT_WA2_END  65536                      // 512*128 float4 units
#define CVT_TOTAL    (CVT_WA2_END + 3*81920)    // 311296
__global__ __launch_bounds__(256) void k_cvt_w(const float* __restrict__ W_attn,
                                               const float* __restrict__ W_cpu,
                                               const float* __restrict__ W_cpm,
                                               const float* __restrict__ W_cppz,
                                               unsigned short* __restrict__ bf) {
    int idx = blockIdx.x * 256 + threadIdx.x;
    if (idx >= CVT_TOTAL) return;
    const float* src;
    unsigned short* dst;
    if (idx < CVT_WA2_END) {
        int g = idx >> 7;                // 128 float4 units per row
        int c = (idx & 127) * 4;
        src = W_attn + (size_t)g * 1024 + 512 + c;
        dst = bf + BF_WA2 + g * 512 + c;
    } else {
        int r = idx - CVT_WA2_END;
        int seg = r / 81920, q = r % 81920;
        const float* s0 = (seg == 0) ? W_cpu : (seg == 1) ? W_cpm : W_cppz;
        src = s0 + (size_t)q * 4;
        dst = bf + BF_WCP + seg * 327680 + q * 4;
    }
    float4 v = *(const float4*)src;
    ushort4 o;
    o.x = f2bf(v.x); o.y = f2bf(v.y); o.z = f2bf(v.z); o.w = f2bf(v.w);
    *(ushort4*)dst = o;
}

// ---------------- K1: q = h0·W_attn[:, :H]^T + b_attn  (MFMA, inline W cvt)
__global__ __launch_bounds__(256) void k_q_mfma(const float* __restrict__ last_h,
                                                const float* __restrict__ W_attn,
                                                const float* __restrict__ b_attn,
                                                float* __restrict__ ws) {
    int tid = threadIdx.x, wave = tid >> 6, lane = tid & 63;
    int m = lane & 31, khalf = lane >> 5;
    int n = blockIdx.x * 128 + wave * 32 + (lane & 31);
    const float* aptr = last_h + (size_t)m * H + khalf * 8;
    const float* bptr = W_attn + (size_t)n * 1024 + khalf * 8;
    f32x16_t acc = {};
    for (int k0 = 0; k0 < 512; k0 += 16) {
        bf16x8_t a = cvt8(aptr + k0);
        bf16x8_t bb = cvt8(bptr + k0);
        acc = __builtin_amdgcn_mfma_f32_32x32x16_bf16(a, bb, acc, 0, 0, 0);
    }
    float bg = b_attn[n];
#pragma unroll
    for (int r = 0; r < 16; ++r) {
        int row = (r & 3) + 8 * (r >> 2) + 4 * khalf;   // b index
        ws[WS_Q + row * H + n] = acc[r] + bg;
    }
}

// ---------------- K2: attn scores via MFMA 16x16x32 ------------------------
__global__ __launch_bounds__(256) void k_attn_mfma(const float* __restrict__ u_h,
                                                   const float* __restrict__ m_h,
                                                   const float* __restrict__ pz_h,
                                                   const unsigned short* __restrict__ bf,
                                                   const float* __restrict__ v_attn,
                                                   float* __restrict__ ws) {
    int blk = blockIdx.x;
    int b = blk / 18, t0 = (blk % 18) * 16;
    int tid = threadIdx.x, wave = tid >> 6, lane = tid & 63;
    int n16 = lane & 15, quad = lane >> 4;
    const float* abase = enc_row(u_h, m_h, pz_h, b, t0) + (size_t)n16 * H + quad * 8;
    const unsigned short* wbase = bf + BF_WA2 + (size_t)quad * 8;
    f32x4_t acc[8];
#pragma unroll
    for (int j = 0; j < 8; ++j) acc[j] = (f32x4_t){0.f, 0.f, 0.f, 0.f};
    for (int k0 = 0; k0 < 512; k0 += 32) {
        bf16x8_t a = cvt8(abase + k0);
#pragma unroll
        for (int j = 0; j < 8; ++j) {
            int g0 = (wave * 8 + j) * 16;
            bf16x8_t bb = *(const bf16x8_t*)(wbase + (size_t)(g0 + n16) * 512 + k0);
            acc[j] = __builtin_amdgcn_mfma_f32_16x16x32_bf16(a, bb, acc[j], 0, 0, 0);
        }
    }
    float sval[4] = {0.f, 0.f, 0.f, 0.f};
#pragma unroll
    for (int j = 0; j < 8; ++j) {
        int g = (wave * 8 + j) * 16 + n16;
        float q = ws[WS_Q + b * H + g];
        float va = v_attn[g];
#pragma unroll
        for (int r = 0; r < 4; ++r) sval[r] += fast_tanh(acc[j][r] + q) * va;
    }
#pragma unroll
    for (int r = 0; r < 4; ++r)
        for (int off = 8; off > 0; off >>= 1) sval[r] += __shfl_down(sval[r], off, 64);
    __shared__ float red[4][16];
    if (n16 == 0)
#pragma unroll
        for (int r = 0; r < 4; ++r) red[wave][quad * 4 + r] = sval[r];
    __syncthreads();
    if (tid < 16)
        ws[WS_SCORE + b * TENC + t0 + tid] =
            red[0][tid] + red[1][tid] + red[2][tid] + red[3][tid];
}

// ---------------- K3: softmax over t and context ---------------------------
__global__ __launch_bounds__(256) void k_softmax_ctx(const float* __restrict__ u_h,
                                                     const float* __restrict__ m_h,
                                                     const float* __restrict__ pz_h,
                                                     float* __restrict__ ws) {
    int b = blockIdx.x, tid = threadIdx.x;
    __shared__ float wsm[TENC];
    __shared__ float red1[4], red2[4];
    float local = -1e30f;
    for (int t = tid; t < TENC; t += 256) {
        float s = ws[WS_SCORE + b * TENC + t];
        wsm[t] = s;
        local = fmaxf(local, s);
    }
    int lane = tid & 63, wv = tid >> 6;
    for (int off = 32; off > 0; off >>= 1) local = fmaxf(local, __shfl_down(local, off, 64));
    if (lane == 0) red1[wv] = local;
    __syncthreads();
    float mx = fmaxf(fmaxf(red1[0], red1[1]), fmaxf(red1[2], red1[3]));
    float ls = 0.f;
    for (int t = tid; t < TENC; t += 256) {
        float e = __expf(wsm[t] - mx);
        wsm[t] = e;
        ls += e;
    }
    for (int off = 32; off > 0; off >>= 1) ls += __shfl_down(ls, off, 64);
    if (lane == 0) red2[wv] = ls;
    __syncthreads();
    float inv = 1.f / (red2[0] + red2[1] + red2[2] + red2[3]);

    int h = blockIdx.y * 256 + tid;
    float acc = 0.f;
#pragma unroll 4
    for (int t = 0; t < TU; ++t) acc += wsm[t] * u_h[((size_t)b * TU + t) * H + h];
#pragma unroll 4
    for (int t = 0; t < TM; ++t) acc += wsm[TU + t] * m_h[((size_t)b * TM + t) * H + h];
#pragma unroll 4
    for (int t = 0; t < TZ; ++t) acc += wsm[TU + TM + t] * pz_h[((size_t)b * TZ + t) * H + h];
    ws[WS_CTX + b * H + h] = acc * inv;
}

// ---------------- K4: GRU gates via MFMA (inline W cvt, W read once) -------
// gi[b,r] = x[b]·W_ih[r], gh[b,r] = h0[b]·W_hh[r]; M=32, N=1536
__global__ __launch_bounds__(256) void k_gru_mfma(const float* __restrict__ emb,
                                                  const float* __restrict__ last_h,
                                                  const float* __restrict__ W_ih,
                                                  const float* __restrict__ W_hh,
                                                  const float* __restrict__ b_ih,
                                                  const float* __restrict__ b_hh,
                                                  float* __restrict__ ws) {
    int tid = threadIdx.x, wave = tid >> 6, lane = tid & 63;
    int m = lane & 31, khalf = lane >> 5;
    int n = blockIdx.x * 128 + wave * 32 + (lane & 31);
    // ih GEMM: K = S = 640, x = [emb(128) | ctx(512)]
    const float* bi_row = W_ih + (size_t)n * S + khalf * 8;
    f32x16_t acc_i = {};
    for (int k0 = 0; k0 < S; k0 += 16) {
        int ks = k0 + khalf * 8;
        const float* ap = (ks < E) ? (emb + m * E + ks)
                                   : (ws + WS_CTX + m * H + (ks - E));
        bf16x8_t a = cvt8(ap);
        bf16x8_t bb = cvt8(bi_row + k0);
        acc_i = __builtin_amdgcn_mfma_f32_32x32x16_bf16(a, bb, acc_i, 0, 0, 0);
    }
    // hh GEMM: K = H = 512
    const float* bh_row = W_hh + (size_t)n * H + khalf * 8;
    const float* ah = last_h + (size_t)m * H + khalf * 8;
    f32x16_t acc_h = {};
    for (int k0 = 0; k0 < H; k0 += 16) {
        bf16x8_t a = cvt8(ah + k0);
        bf16x8_t bb = cvt8(bh_row + k0);
        acc_h = __builtin_amdgcn_mfma_f32_32x32x16_bf16(a, bb, acc_h, 0, 0, 0);
    }
    float bi = b_ih[n], bh = b_hh[n];
#pragma unroll
    for (int r = 0; r < 16; ++r) {
        int row = (r & 3) + 8 * (r >> 2) + 4 * khalf;   // b index
        ws[WS_GI + row * G3 + n] = acc_i[r] + bi;
        ws[WS_GH + row * G3 + n] = acc_h[r] + bh;
    }
}

// ---------------- K5: GRU pointwise ---------------------------------------
__global__ __launch_bounds__(256) void k_gru_combine(const float* __restrict__ emb,
                                                     const float* __restrict__ last_hidden,
                                                     float* __restrict__ ws,
                                                     float* __restrict__ out) {
    int i = blockIdx.x * 256 + threadIdx.x;
    int b = i >> 9, h = i & 511;
    float gi_r = ws[WS_GI + b * G3 + h];
    float gi_z = ws[WS_GI + b * G3 + H + h];
    float gi_n = ws[WS_GI + b * G3 + 2 * H + h];
    float gh_r = ws[WS_GH + b * G3 + h];
    float gh_z = ws[WS_GH + b * G3 + H + h];
    float gh_n = ws[WS_GH + b * G3 + 2 * H + h];
    float rr = 1.f / (1.f + __expf(-(gi_r + gh_r)));
    float zz = 1.f / (1.f + __expf(-(gi_z + gh_z)));
    float nn = fast_tanh(gi_n + rr * gh_n);
    float hp = last_hidden[b * H + h];
    float hn = (1.f - zz) * nn + zz * hp;
    out[V * B + b * H + h] = hn;
    out[V * B + B * H + b * H + h] = hn;
    ws[WS_ST + b * S + h] = hn;
    if (h < E) ws[WS_ST + b * S + H + h] = emb[b * E + h];
}

// ---------------- K6: copy scores via MFMA 16x16x32 ------------------------
__global__ __launch_bounds__(256) void k_copy_mfma(const float* __restrict__ u_h,
                                                   const float* __restrict__ m_h,
                                                   const float* __restrict__ pz_h,
                                                   const unsigned short* __restrict__ bf,
                                                   const float* __restrict__ b_cpu,
                                                   const float* __restrict__ b_cpm,
                                                   const float* __restrict__ b_cppz,
                                                   float* __restrict__ ws) {
    int blk = blockIdx.x;
    int b = blk / 18, t0 = (blk % 18) * 16;
    int tid = threadIdx.x, wave = tid >> 6, lane = tid & 63;
    int n16 = lane & 15, quad = lane >> 4;
    int seg = (t0 < TU) ? 0 : (t0 < TU + TM) ? 1 : 2;
    const float* bias = (seg == 0) ? b_cpu : (seg == 1) ? b_cpm : b_cppz;
    const float* abase = enc_row(u_h, m_h, pz_h, b, t0) + (size_t)n16 * H + quad * 8;
    const unsigned short* wbase = bf + BF_WCP + (size_t)seg * 327680 + (size_t)quad * 8;
    f32x4_t acc[10];
#pragma unroll
    for (int j = 0; j < 10; ++j) acc[j] = (f32x4_t){0.f, 0.f, 0.f, 0.f};
    for (int k0 = 0; k0 < 512; k0 += 32) {
        bf16x8_t a = cvt8(abase + k0);
#pragma unroll
        for (int j = 0; j < 10; ++j) {
            int s0 = (wave * 10 + j) * 16;
            bf16x8_t bb = *(const bf16x8_t*)(wbase + (size_t)(s0 + n16) * 512 + k0);
            acc[j] = __builtin_amdgcn_mfma_f32_16x16x32_bf16(a, bb, acc[j], 0, 0, 0);
        }
    }
    float sval[4] = {0.f, 0.f, 0.f, 0.f};
#pragma unroll
    for (int j = 0; j < 10; ++j) {
        int s = (wave * 10 + j) * 16 + n16;
        float bi = bias[s];
        float st = ws[WS_ST + b * S + s];
#pragma unroll
        for (int r = 0; r < 4; ++r) sval[r] += fast_tanh(acc[j][r] + bi) * st;
    }
#pragma unroll
    for (int r = 0; r < 4; ++r)
        for (int off = 8; off > 0; off >>= 1) sval[r] += __shfl_down(sval[r], off, 64);
    __shared__ float red[4][16];
    if (n16 == 0)
#pragma unroll
        for (int r = 0; r < 4; ++r) red[wave][quad * 4 + r] = sval[r];
    __syncthreads();
    if (tid < 16)
        ws[WS_LOGIT + (size_t)b * NLOG + V + t0 + tid] =
            red[0][tid] + red[1][tid] + red[2][tid] + red[3][tid];
}

// ---------------- K7: score_g via MFMA (inline W_gen cvt, read once) -------
__global__ __launch_bounds__(256) void k_score_g_mfma(const float* __restrict__ W_gen,
                                                      const float* __restrict__ b_gen,
                                                      float* __restrict__ ws) {
    int tid = threadIdx.x, wave = tid >> 6, lane = tid & 63;
    int m = lane & 31, khalf = lane >> 5;
    int n = blockIdx.x * 128 + wave * 32 + (lane & 31);
    int nr = (n < V) ? n : (V - 1);
    const float* aptr = ws + WS_ST + (size_t)m * S + khalf * 8;
    const float* bptr = W_gen + (size_t)nr * S + khalf * 8;
    f32x16_t acc = {};
    for (int k0 = 0; k0 < S; k0 += 16) {
        bf16x8_t a = cvt8(aptr + k0);
        bf16x8_t bb = cvt8(bptr + k0);
        acc = __builtin_amdgcn_mfma_f32_32x32x16_bf16(a, bb, acc, 0, 0, 0);
    }
    if (n >= V) return;
    float bg = b_gen[n];
#pragma unroll
    for (int r = 0; r < 16; ++r) {
        int row = (r & 3) + 8 * (r >> 2) + 4 * khalf;   // b index
        ws[WS_LOGIT + (size_t)row * NLOG + n] = acc[r] + bg;
    }
}

// ---------------- K8: final softmax + one-hot scatter (fused) --------------
__global__ __launch_bounds__(256) void k_softmax_scatter(const int* __restrict__ u_in,
                                                         const int* __restrict__ m_in,
                                                         float* __restrict__ ws,
                                                         float* __restrict__ out) {
    int b = blockIdx.x, tid = threadIdx.x;
    __shared__ float red1[4], red2[4];
    __shared__ float pcopy[TENC];
    const float* lg = ws + WS_LOGIT + (size_t)b * NLOG;
    float mx = -1e30f;
    for (int i = tid; i < NLOG; i += 256) mx = fmaxf(mx, lg[i]);
    int lane = tid & 63, wv = tid >> 6;
    for (int off = 32; off > 0; off >>= 1) mx = fmaxf(mx, __shfl_down(mx, off, 64));
    if (lane == 0) red1[wv] = mx;
    __syncthreads();
    mx = fmaxf(fmaxf(red1[0], red1[1]), fmaxf(red1[2], red1[3]));
    float sm = 0.f;
    for (int i = tid; i < NLOG; i += 256) sm += __expf(lg[i] - mx);
    for (int off = 32; off > 0; off >>= 1) sm += __shfl_down(sm, off, 64);
    if (lane == 0) red2[wv] = sm;
    __syncthreads();
    float inv = 1.f / (red2[0] + red2[1] + red2[2] + red2[3]);
    for (int i = tid; i < NLOG; i += 256) {
        float p = __expf(lg[i] - mx) * inv;
        if (i < V) out[b * V + i] = p;
        else pcopy[i - V] = p;
    }
    __syncthreads();   // all p_g stores drained before atomics (vmcnt(0)+barrier)
    if (tid < TU + TM) {
        int idx = (tid < TU) ? u_in[b * TU + tid] : m_in[b * TM + (tid - TU)];
        atomicAdd(&out[(size_t)b * V + idx], pcopy[tid]);
    } else if (tid < TENC) {
        ws[WS_PCOPY + b * TENC + tid] = pcopy[tid];   // TZ slice for k_pv
    }
}

// ---------------- K9: dense pv_z_prob accumulation -------------------------
__global__ __launch_bounds__(256) void k_pv(const float* __restrict__ pvp,
                                            const float* __restrict__ ws,
                                            float* __restrict__ out) {
    int b = blockIdx.y;
    int v = blockIdx.x * 256 + threadIdx.x;
    __shared__ float p[TZ];
    if (threadIdx.x < TZ) p[threadIdx.x] = ws[WS_PCOPY + b * TENC + TU + TM + threadIdx.x];
    __syncthreads();
    if (v >= V) return;
    float acc = 0.f;
#pragma unroll 4
    for (int t = 0; t < TZ; ++t) acc += p[t] * pvp[((size_t)b * TZ + t) * V + v];
    out[(size_t)b * V + v] += acc;
}

extern "C" void kernel_launch(void* const* d_in, const int* in_sizes, int n_in,
                              void* d_out, int out_size, void* d_ws, size_t ws_size,
                              hipStream_t stream) {
    const int*   u_input   = (const int*)d_in[0];
    const float* u_h       = (const float*)d_in[2];
    const int*   m_input   = (const int*)d_in[3];
    const float* m_h       = (const float*)d_in[5];
    const float* pv_prob   = (const float*)d_in[6];
    const float* pz_h      = (const float*)d_in[7];
    const float* emb       = (const float*)d_in[9];
    const float* last_h    = (const float*)d_in[10];
    const float* W_attn    = (const float*)d_in[11];
    const float* b_attn    = (const float*)d_in[12];
    const float* v_attn    = (const float*)d_in[13];
    const float* W_ih      = (const float*)d_in[14];
    const float* W_hh      = (const float*)d_in[15];
    const float* b_ih      = (const float*)d_in[16];
    const float* b_hh      = (const float*)d_in[17];
    const float* W_gen     = (const float*)d_in[18];
    const float* b_gen     = (const float*)d_in[19];
    const float* W_cpu     = (const float*)d_in[20];
    const float* b_cpu     = (const float*)d_in[21];
    const float* W_cpm     = (const float*)d_in[22];
    const float* b_cpm     = (const float*)d_in[23];
    const float* W_cppz    = (const float*)d_in[24];
    const float* b_cppz    = (const float*)d_in[25];
    float* ws  = (float*)d_ws;
    unsigned short* bf = (unsigned short*)(ws + WS_F_TOTAL);
    float* out = (float*)d_out;

    hipLaunchKernelGGL(k_cvt_w, dim3((CVT_TOTAL + 255) / 256), dim3(256), 0, stream,
                       W_attn, W_cpu, W_cpm, W_cppz, bf);
    hipLaunchKernelGGL(k_q_mfma, dim3(4), dim3(256), 0, stream, last_h, W_attn, b_attn, ws);
    hipLaunchKernelGGL(k_attn_mfma, dim3(B * 18), dim3(256), 0, stream,
                       u_h, m_h, pz_h, bf, v_attn, ws);
    hipLaunchKernelGGL(k_softmax_ctx, dim3(B, 2), dim3(256), 0, stream, u_h, m_h, pz_h, ws);
    hipLaunchKernelGGL(k_gru_mfma, dim3(12), dim3(256), 0, stream,
                       emb, last_h, W_ih, W_hh, b_ih, b_hh, ws);
    hipLaunchKernelGGL(k_gru_combine, dim3(64), dim3(256), 0, stream, emb, last_h, ws, out);
    hipLaunchKernelGGL(k_copy_mfma, dim3(B * 18), dim3(256), 0, stream,
                       u_h, m_h, pz_h, bf, b_cpu, b_cpm, b_cppz, ws);
    hipLaunchKernelGGL(k_score_g_mfma, dim3((V + 127) / 128), dim3(256), 0, stream,
                       W_gen, b_gen, ws);
    hipLaunchKernelGGL(k_softmax_scatter, dim3(B), dim3(256), 0, stream,
                       u_input, m_input, ws, out);
    hipLaunchKernelGGL(k_pv, dim3(40, B), dim3(256), 0, stream, pv_prob, ws, out);
}

// Round 5
// 576.376 us; speedup vs baseline: 1.0628x; 1.0628x over previous
//
#include <hip/hip_runtime.h>
#include <math.h>

// Problem constants
#define B   32
#define TU  128
#define TM  128
#define TZ  32
#define TENC 288
#define V   10000
#define H   512
#define E   128
#define S   640          // E + H
#define G3  1536         // 3*H
#define NLOG (V + TENC)  // 10288

// Workspace float region (float offsets)
#define WS_Q      0                       // B*H
#define WS_SCORE  (WS_Q + B*H)            // B*TENC
#define WS_CTX    (WS_SCORE + B*TENC)     // B*H
#define WS_GI     (WS_CTX + B*H)          // B*G3
#define WS_GH     (WS_GI + B*G3)          // B*G3
#define WS_ST     (WS_GH + B*G3)          // B*S
#define WS_LOGIT  (WS_ST + B*S)           // B*NLOG
#define WS_PCOPY  (WS_LOGIT + B*NLOG)     // B*TENC
#define WS_F_TOTAL (WS_PCOPY + B*TENC)    // 499200 floats (16B-aligned)

// bf16 (ushort) region, offsets from bf = (ushort*)(ws + WS_F_TOTAL).
// Weights & enc stored K-TILED: [k/32][row][32] so a wave's MFMA fragment
// set (16 rows x 32 k x 2B = 1KB) is contiguous -> fully coalesced.
#define BF_WA2  0                         // W_attn[:,H:] 16 tiles x 512 x 32
#define BF_WCP  (BF_WA2 + 512*512)        // 3 segs, each 16 tiles x 640 x 32
#define BF_ENC  (BF_WCP + 3*640*512)      // [b][k/32][t 288][32]
#define BF_ST   (BF_ENC + B*TENC*H)       // [b][s 640]

typedef __attribute__((ext_vector_type(8))) short bf16x8_t;
typedef __attribute__((ext_vector_type(4))) float f32x4_t;
typedef __attribute__((ext_vector_type(16))) float f32x16_t;

__device__ __forceinline__ float fast_tanh(float x) {
    return 1.f - 2.f / (__expf(2.f * x) + 1.f);
}

__device__ __forceinline__ unsigned short f2bf(float x) {
    unsigned int u = __float_as_uint(x);
    u += 0x7fffu + ((u >> 16) & 1u);   // RNE
    return (unsigned short)(u >> 16);
}

__device__ __forceinline__ float bf2f(unsigned short u) {
    return __uint_as_float(((unsigned int)u) << 16);
}

// 8 consecutive fp32 -> bf16x8 fragment (used only in cold/low-reuse paths)
__device__ __forceinline__ bf16x8_t cvt8(const float* p) {
    float4 a = *(const float4*)(p);
    float4 b = *(const float4*)(p + 4);
    bf16x8_t r;
    r[0] = (short)f2bf(a.x); r[1] = (short)f2bf(a.y);
    r[2] = (short)f2bf(a.z); r[3] = (short)f2bf(a.w);
    r[4] = (short)f2bf(b.x); r[5] = (short)f2bf(b.y);
    r[6] = (short)f2bf(b.z); r[7] = (short)f2bf(b.w);
    return r;
}

__device__ __forceinline__ const float* enc_row(const float* u, const float* m,
                                                const float* pz, int b, int t) {
    if (t < TU) return u + ((size_t)b * TU + t) * H;
    if (t < TU + TM) return m + ((size_t)b * TM + (t - TU)) * H;
    return pz + ((size_t)b * TZ + (t - TU - TM)) * H;
}

// ---------------- K0a: weight cvt + k-tile swizzle -------------------------
#define CVT_WA2_END  65536                      // 512 g x 128 float4 units
#define CVT_TOTAL    (CVT_WA2_END + 3*81920)    // 311296
__global__ __launch_bounds__(256) void k_cvt_w(const float* __restrict__ W_attn,
                                               const float* __restrict__ W_cpu,
                                               const float* __restrict__ W_cpm,
                                               const float* __restrict__ W_cppz,
                                               unsigned short* __restrict__ bf) {
    int idx = blockIdx.x * 256 + threadIdx.x;
    if (idx >= CVT_TOTAL) return;
    const float* src;
    unsigned short* dst;
    if (idx < CVT_WA2_END) {
        int g = idx >> 7, c4 = idx & 127;
        int k = c4 * 4, kt = k >> 5, kin = k & 31;
        src = W_attn + (size_t)g * 1024 + 512 + k;
        dst = bf + BF_WA2 + kt * (512 * 32) + g * 32 + kin;
    } else {
        int r = idx - CVT_WA2_END;
        int seg = r / 81920, q = r % 81920;
        int s = q >> 7, c4 = q & 127;
        int k = c4 * 4, kt = k >> 5, kin = k & 31;
        const float* s0 = (seg == 0) ? W_cpu : (seg == 1) ? W_cpm : W_cppz;
        src = s0 + (size_t)s * 512 + k;
        dst = bf + BF_WCP + seg * 327680 + kt * (640 * 32) + s * 32 + kin;
    }
    float4 v = *(const float4*)src;
    ushort4 o;
    o.x = f2bf(v.x); o.y = f2bf(v.y); o.z = f2bf(v.z); o.w = f2bf(v.w);
    *(ushort4*)dst = o;
}

// ---------------- K0b: enc cvt + k-tile swizzle ----------------------------
#define CVTE_TOTAL (B * TENC * 128)             // 1179648 float4 units
__global__ __launch_bounds__(256) void k_cvt_enc(const float* __restrict__ u_h,
                                                 const float* __restrict__ m_h,
                                                 const float* __restrict__ pz_h,
                                                 unsigned short* __restrict__ bf) {
    int idx = blockIdx.x * 256 + threadIdx.x;
    if (idx >= CVTE_TOTAL) return;
    int b = idx / (TENC * 128);
    int r = idx % (TENC * 128);
    int t = r >> 7, c4 = r & 127;
    int k = c4 * 4, kt = k >> 5, kin = k & 31;
    const float* src = enc_row(u_h, m_h, pz_h, b, t) + k;
    unsigned short* dst = bf + BF_ENC + (((size_t)b * 16 + kt) * TENC + t) * 32 + kin;
    float4 v = *(const float4*)src;
    ushort4 o;
    o.x = f2bf(v.x); o.y = f2bf(v.y); o.z = f2bf(v.z); o.w = f2bf(v.w);
    *(ushort4*)dst = o;
}

// ---------------- K1: q = h0·W_attn[:, :H]^T + b_attn  (MFMA, inline cvt) --
__global__ __launch_bounds__(256) void k_q_mfma(const float* __restrict__ last_h,
                                                const float* __restrict__ W_attn,
                                                const float* __restrict__ b_attn,
                                                float* __restrict__ ws) {
    int tid = threadIdx.x, wave = tid >> 6, lane = tid & 63;
    int m = lane & 31, khalf = lane >> 5;
    int n = blockIdx.x * 128 + wave * 32 + (lane & 31);
    const float* aptr = last_h + (size_t)m * H + khalf * 8;
    const float* bptr = W_attn + (size_t)n * 1024 + khalf * 8;
    f32x16_t acc = {};
    for (int k0 = 0; k0 < 512; k0 += 16) {
        bf16x8_t a = cvt8(aptr + k0);
        bf16x8_t bb = cvt8(bptr + k0);
        acc = __builtin_amdgcn_mfma_f32_32x32x16_bf16(a, bb, acc, 0, 0, 0);
    }
    float bg = b_attn[n];
#pragma unroll
    for (int r = 0; r < 16; ++r) {
        int row = (r & 3) + 8 * (r >> 2) + 4 * khalf;   // b index
        ws[WS_Q + row * H + n] = acc[r] + bg;
    }
}

// ---------------- K2: attn scores, bf16 swizzled A and B -------------------
__global__ __launch_bounds__(256) void k_attn_mfma(const unsigned short* __restrict__ bf,
                                                   const float* __restrict__ v_attn,
                                                   float* __restrict__ ws) {
    int blk = blockIdx.x;
    int b = blk / 18, t0 = (blk % 18) * 16;
    int tid = threadIdx.x, wave = tid >> 6, lane = tid & 63;
    int n16 = lane & 15, quad = lane >> 4;
    // A: [b][kt][t][32]; lane fragment = row t0+n16, shorts quad*8..+8
    const unsigned short* abase =
        bf + BF_ENC + (((size_t)b * 16) * TENC + t0 + n16) * 32 + quad * 8;
    const unsigned short* wbase = bf + BF_WA2 + n16 * 32 + quad * 8;
    f32x4_t acc[8];
#pragma unroll
    for (int j = 0; j < 8; ++j) acc[j] = (f32x4_t){0.f, 0.f, 0.f, 0.f};
    for (int kt = 0; kt < 16; ++kt) {
        bf16x8_t a = *(const bf16x8_t*)(abase + (size_t)kt * TENC * 32);
        const unsigned short* wk = wbase + (size_t)kt * 512 * 32;
#pragma unroll
        for (int j = 0; j < 8; ++j) {
            bf16x8_t bb = *(const bf16x8_t*)(wk + (wave * 8 + j) * 16 * 32);
            acc[j] = __builtin_amdgcn_mfma_f32_16x16x32_bf16(a, bb, acc[j], 0, 0, 0);
        }
    }
    float sval[4] = {0.f, 0.f, 0.f, 0.f};
#pragma unroll
    for (int j = 0; j < 8; ++j) {
        int g = (wave * 8 + j) * 16 + n16;
        float q = ws[WS_Q + b * H + g];
        float va = v_attn[g];
#pragma unroll
        for (int r = 0; r < 4; ++r) sval[r] += fast_tanh(acc[j][r] + q) * va;
    }
#pragma unroll
    for (int r = 0; r < 4; ++r)
        for (int off = 8; off > 0; off >>= 1) sval[r] += __shfl_down(sval[r], off, 64);
    __shared__ float red[4][16];
    if (n16 == 0)
#pragma unroll
        for (int r = 0; r < 4; ++r) red[wave][quad * 4 + r] = sval[r];
    __syncthreads();
    if (tid < 16)
        ws[WS_SCORE + b * TENC + t0 + tid] =
            red[0][tid] + red[1][tid] + red[2][tid] + red[3][tid];
}

// ---------------- K3: softmax over t and context (bf16 enc) ----------------
__global__ __launch_bounds__(256) void k_softmax_ctx(const unsigned short* __restrict__ bf,
                                                     float* __restrict__ ws) {
    int b = blockIdx.x, tid = threadIdx.x;
    __shared__ float wsm[TENC];
    __shared__ float red1[4], red2[4];
    float local = -1e30f;
    for (int t = tid; t < TENC; t += 256) {
        float s = ws[WS_SCORE + b * TENC + t];
        wsm[t] = s;
        local = fmaxf(local, s);
    }
    int lane = tid & 63, wv = tid >> 6;
    for (int off = 32; off > 0; off >>= 1) local = fmaxf(local, __shfl_down(local, off, 64));
    if (lane == 0) red1[wv] = local;
    __syncthreads();
    float mx = fmaxf(fmaxf(red1[0], red1[1]), fmaxf(red1[2], red1[3]));
    float ls = 0.f;
    for (int t = tid; t < TENC; t += 256) {
        float e = __expf(wsm[t] - mx);
        wsm[t] = e;
        ls += e;
    }
    for (int off = 32; off > 0; off >>= 1) ls += __shfl_down(ls, off, 64);
    if (lane == 0) red2[wv] = ls;
    __syncthreads();
    float inv = 1.f / (red2[0] + red2[1] + red2[2] + red2[3]);

    int h = blockIdx.y * 256 + tid;
    int kt = h >> 5, hin = h & 31;
    const unsigned short* ep = bf + BF_ENC + ((size_t)b * 16 + kt) * TENC * 32 + hin;
    float acc = 0.f;
#pragma unroll 4
    for (int t = 0; t < TENC; ++t) acc += wsm[t] * bf2f(ep[t * 32]);
    ws[WS_CTX + b * H + h] = acc * inv;
}

// ---------------- K4: GRU gates via MFMA (inline cvt, W read once) ---------
__global__ __launch_bounds__(256) void k_gru_mfma(const float* __restrict__ emb,
                                                  const float* __restrict__ last_h,
                                                  const float* __restrict__ W_ih,
                                                  const float* __restrict__ W_hh,
                                                  const float* __restrict__ b_ih,
                                                  const float* __restrict__ b_hh,
                                                  float* __restrict__ ws) {
    int tid = threadIdx.x, wave = tid >> 6, lane = tid & 63;
    int m = lane & 31, khalf = lane >> 5;
    int n = blockIdx.x * 128 + wave * 32 + (lane & 31);
    const float* bi_row = W_ih + (size_t)n * S + khalf * 8;
    f32x16_t acc_i = {};
    for (int k0 = 0; k0 < S; k0 += 16) {
        int ks = k0 + khalf * 8;
        const float* ap = (ks < E) ? (emb + m * E + ks)
                                   : (ws + WS_CTX + m * H + (ks - E));
        bf16x8_t a = cvt8(ap);
        bf16x8_t bb = cvt8(bi_row + k0);
        acc_i = __builtin_amdgcn_mfma_f32_32x32x16_bf16(a, bb, acc_i, 0, 0, 0);
    }
    const float* bh_row = W_hh + (size_t)n * H + khalf * 8;
    const float* ah = last_h + (size_t)m * H + khalf * 8;
    f32x16_t acc_h = {};
    for (int k0 = 0; k0 < H; k0 += 16) {
        bf16x8_t a = cvt8(ah + k0);
        bf16x8_t bb = cvt8(bh_row + k0);
        acc_h = __builtin_amdgcn_mfma_f32_32x32x16_bf16(a, bb, acc_h, 0, 0, 0);
    }
    float bi = b_ih[n], bh = b_hh[n];
#pragma unroll
    for (int r = 0; r < 16; ++r) {
        int row = (r & 3) + 8 * (r >> 2) + 4 * khalf;   // b index
        ws[WS_GI + row * G3 + n] = acc_i[r] + bi;
        ws[WS_GH + row * G3 + n] = acc_h[r] + bh;
    }
}

// ---------------- K5: GRU pointwise; emits fp32 st and bf16 st -------------
__global__ __launch_bounds__(256) void k_gru_combine(const float* __restrict__ emb,
                                                     const float* __restrict__ last_hidden,
                                                     float* __restrict__ ws,
                                                     unsigned short* __restrict__ bf,
                                                     float* __restrict__ out) {
    int i = blockIdx.x * 256 + threadIdx.x;
    int b = i >> 9, h = i & 511;
    float gi_r = ws[WS_GI + b * G3 + h];
    float gi_z = ws[WS_GI + b * G3 + H + h];
    float gi_n = ws[WS_GI + b * G3 + 2 * H + h];
    float gh_r = ws[WS_GH + b * G3 + h];
    float gh_z = ws[WS_GH + b * G3 + H + h];
    float gh_n = ws[WS_GH + b * G3 + 2 * H + h];
    float rr = 1.f / (1.f + __expf(-(gi_r + gh_r)));
    float zz = 1.f / (1.f + __expf(-(gi_z + gh_z)));
    float nn = fast_tanh(gi_n + rr * gh_n);
    float hp = last_hidden[b * H + h];
    float hn = (1.f - zz) * nn + zz * hp;
    out[V * B + b * H + h] = hn;
    out[V * B + B * H + b * H + h] = hn;
    ws[WS_ST + b * S + h] = hn;
    bf[BF_ST + b * S + h] = f2bf(hn);
    if (h < E) {
        float ev = emb[b * E + h];
        ws[WS_ST + b * S + H + h] = ev;
        bf[BF_ST + b * S + H + h] = f2bf(ev);
    }
}

// ---------------- K6: copy scores, bf16 swizzled A and B -------------------
__global__ __launch_bounds__(256) void k_copy_mfma(const unsigned short* __restrict__ bf,
                                                   const float* __restrict__ b_cpu,
                                                   const float* __restrict__ b_cpm,
                                                   const float* __restrict__ b_cppz,
                                                   float* __restrict__ ws) {
    int blk = blockIdx.x;
    int b = blk / 18, t0 = (blk % 18) * 16;
    int tid = threadIdx.x, wave = tid >> 6, lane = tid & 63;
    int n16 = lane & 15, quad = lane >> 4;
    int seg = (t0 < TU) ? 0 : (t0 < TU + TM) ? 1 : 2;
    const float* bias = (seg == 0) ? b_cpu : (seg == 1) ? b_cpm : b_cppz;
    const unsigned short* abase =
        bf + BF_ENC + (((size_t)b * 16) * TENC + t0 + n16) * 32 + quad * 8;
    const unsigned short* wbase = bf + BF_WCP + seg * 327680 + n16 * 32 + quad * 8;
    f32x4_t acc[10];
#pragma unroll
    for (int j = 0; j < 10; ++j) acc[j] = (f32x4_t){0.f, 0.f, 0.f, 0.f};
    for (int kt = 0; kt < 16; ++kt) {
        bf16x8_t a = *(const bf16x8_t*)(abase + (size_t)kt * TENC * 32);
        const unsigned short* wk = wbase + (size_t)kt * 640 * 32;
#pragma unroll
        for (int j = 0; j < 10; ++j) {
            bf16x8_t bb = *(const bf16x8_t*)(wk + (wave * 10 + j) * 16 * 32);
            acc[j] = __builtin_amdgcn_mfma_f32_16x16x32_bf16(a, bb, acc[j], 0, 0, 0);
        }
    }
    float sval[4] = {0.f, 0.f, 0.f, 0.f};
#pragma unroll
    for (int j = 0; j < 10; ++j) {
        int s = (wave * 10 + j) * 16 + n16;
        float bi = bias[s];
        float st = ws[WS_ST + b * S + s];
#pragma unroll
        for (int r = 0; r < 4; ++r) sval[r] += fast_tanh(acc[j][r] + bi) * st;
    }
#pragma unroll
    for (int r = 0; r < 4; ++r)
        for (int off = 8; off > 0; off >>= 1) sval[r] += __shfl_down(sval[r], off, 64);
    __shared__ float red[4][16];
    if (n16 == 0)
#pragma unroll
        for (int r = 0; r < 4; ++r) red[wave][quad * 4 + r] = sval[r];
    __syncthreads();
    if (tid < 16)
        ws[WS_LOGIT + (size_t)b * NLOG + V + t0 + tid] =
            red[0][tid] + red[1][tid] + red[2][tid] + red[3][tid];
}

// ---------------- K7: score_g via MFMA (bf16 st A, inline W_gen cvt) -------
__global__ __launch_bounds__(256) void k_score_g_mfma(const unsigned short* __restrict__ bf,
                                                      const float* __restrict__ W_gen,
                                                      const float* __restrict__ b_gen,
                                                      float* __restrict__ ws) {
    int tid = threadIdx.x, wave = tid >> 6, lane = tid & 63;
    int m = lane & 31, khalf = lane >> 5;
    int n = blockIdx.x * 128 + wave * 32 + (lane & 31);
    int nr = (n < V) ? n : (V - 1);
    const unsigned short* aptr = bf + BF_ST + (size_t)m * S + khalf * 8;
    const float* bptr = W_gen + (size_t)nr * S + khalf * 8;
    f32x16_t acc = {};
    for (int k0 = 0; k0 < S; k0 += 16) {
        bf16x8_t a = *(const bf16x8_t*)(aptr + k0);
        bf16x8_t bb = cvt8(bptr + k0);
        acc = __builtin_amdgcn_mfma_f32_32x32x16_bf16(a, bb, acc, 0, 0, 0);
    }
    if (n >= V) return;
    float bg = b_gen[n];
#pragma unroll
    for (int r = 0; r < 16; ++r) {
        int row = (r & 3) + 8 * (r >> 2) + 4 * khalf;   // b index
        ws[WS_LOGIT + (size_t)row * NLOG + n] = acc[r] + bg;
    }
}

// ---------------- K8: final softmax + one-hot scatter (fused) --------------
__global__ __launch_bounds__(256) void k_softmax_scatter(const int* __restrict__ u_in,
                                                         const int* __restrict__ m_in,
                                                         float* __restrict__ ws,
                                                         float* __restrict__ out) {
    int b = blockIdx.x, tid = threadIdx.x;
    __shared__ float red1[4], red2[4];
    __shared__ float pcopy[TENC];
    const float* lg = ws + WS_LOGIT + (size_t)b * NLOG;
    float mx = -1e30f;
    for (int i = tid; i < NLOG; i += 256) mx = fmaxf(mx, lg[i]);
    int lane = tid & 63, wv = tid >> 6;
    for (int off = 32; off > 0; off >>= 1) mx = fmaxf(mx, __shfl_down(mx, off, 64));
    if (lane == 0) red1[wv] = mx;
    __syncthreads();
    mx = fmaxf(fmaxf(red1[0], red1[1]), fmaxf(red1[2], red1[3]));
    float sm = 0.f;
    for (int i = tid; i < NLOG; i += 256) sm += __expf(lg[i] - mx);
    for (int off = 32; off > 0; off >>= 1) sm += __shfl_down(sm, off, 64);
    if (lane == 0) red2[wv] = sm;
    __syncthreads();
    float inv = 1.f / (red2[0] + red2[1] + red2[2] + red2[3]);
    for (int i = tid; i < NLOG; i += 256) {
        float p = __expf(lg[i] - mx) * inv;
        if (i < V) out[b * V + i] = p;
        else pcopy[i - V] = p;
    }
    __syncthreads();
    if (tid < TU + TM) {
        int idx = (tid < TU) ? u_in[b * TU + tid] : m_in[b * TM + (tid - TU)];
        atomicAdd(&out[(size_t)b * V + idx], pcopy[tid]);
    } else if (tid < TENC) {
        ws[WS_PCOPY + b * TENC + tid] = pcopy[tid];   // TZ slice for k_pv
    }
}

// ---------------- K9: dense pv_z_prob accumulation -------------------------
__global__ __launch_bounds__(256) void k_pv(const float* __restrict__ pvp,
                                            const float* __restrict__ ws,
                                            float* __restrict__ out) {
    int b = blockIdx.y;
    int v = blockIdx.x * 256 + threadIdx.x;
    __shared__ float p[TZ];
    if (threadIdx.x < TZ) p[threadIdx.x] = ws[WS_PCOPY + b * TENC + TU + TM + threadIdx.x];
    __syncthreads();
    if (v >= V) return;
    float acc = 0.f;
#pragma unroll 4
    for (int t = 0; t < TZ; ++t) acc += p[t] * pvp[((size_t)b * TZ + t) * V + v];
    out[(size_t)b * V + v] += acc;
}

extern "C" void kernel_launch(void* const* d_in, const int* in_sizes, int n_in,
                              void* d_out, int out_size, void* d_ws, size_t ws_size,
                              hipStream_t stream) {
    const int*   u_input   = (const int*)d_in[0];
    const float* u_h       = (const float*)d_in[2];
    const int*   m_input   = (const int*)d_in[3];
    const float* m_h       = (const float*)d_in[5];
    const float* pv_prob   = (const float*)d_in[6];
    const float* pz_h      = (const float*)d_in[7];
    const float* emb       = (const float*)d_in[9];
    const float* last_h    = (const float*)d_in[10];
    const float* W_attn    = (const float*)d_in[11];
    const float* b_attn    = (const float*)d_in[12];
    const float* v_attn    = (const float*)d_in[13];
    const float* W_ih      = (const float*)d_in[14];
    const float* W_hh      = (const float*)d_in[15];
    const float* b_ih      = (const float*)d_in[16];
    const float* b_hh      = (const float*)d_in[17];
    const float* W_gen     = (const float*)d_in[18];
    const float* b_gen     = (const float*)d_in[19];
    const float* W_cpu     = (const float*)d_in[20];
    const float* b_cpu     = (const float*)d_in[21];
    const float* W_cpm     = (const float*)d_in[22];
    const float* b_cpm     = (const float*)d_in[23];
    const float* W_cppz    = (const float*)d_in[24];
    const float* b_cppz    = (const float*)d_in[25];
    float* ws  = (float*)d_ws;
    unsigned short* bf = (unsigned short*)(ws + WS_F_TOTAL);
    float* out = (float*)d_out;

    hipLaunchKernelGGL(k_cvt_w, dim3((CVT_TOTAL + 255) / 256), dim3(256), 0, stream,
                       W_attn, W_cpu, W_cpm, W_cppz, bf);
    hipLaunchKernelGGL(k_cvt_enc, dim3((CVTE_TOTAL + 255) / 256), dim3(256), 0, stream,
                       u_h, m_h, pz_h, bf);
    hipLaunchKernelGGL(k_q_mfma, dim3(4), dim3(256), 0, stream, last_h, W_attn, b_attn, ws);
    hipLaunchKernelGGL(k_attn_mfma, dim3(B * 18), dim3(256), 0, stream, bf, v_attn, ws);
    hipLaunchKernelGGL(k_softmax_ctx, dim3(B, 2), dim3(256), 0, stream, bf, ws);
    hipLaunchKernelGGL(k_gru_mfma, dim3(12), dim3(256), 0, stream,
                       emb, last_h, W_ih, W_hh, b_ih, b_hh, ws);
    hipLaunchKernelGGL(k_gru_combine, dim3(64), dim3(256), 0, stream, emb, last_h, ws, bf, out);
    hipLaunchKernelGGL(k_copy_mfma, dim3(B * 18), dim3(256), 0, stream,
                       bf, b_cpu, b_cpm, b_cppz, ws);
    hipLaunchKernelGGL(k_score_g_mfma, dim3((V + 127) / 128), dim3(256), 0, stream,
                       bf, W_gen, b_gen, ws);
    hipLaunchKernelGGL(k_softmax_scatter, dim3(B), dim3(256), 0, stream,
                       u_input, m_input, ws, out);
    hipLaunchKernelGGL(k_pv, dim3(40, B), dim3(256), 0, stream, pv_prob, ws, out);
}